// Round 21
// baseline (615.552 us; speedup 1.0000x reference)
//
#include <hip/hip_runtime.h>
#include <math.h>

#define DM 1024
#define DF 4096
#define NE 24
#define T_TOK 4096
#define T2 (T_TOK*2)

#define BM 128
#define BN 128
#define BK 64
#define NK1 (DM / BK)       // 16
#define NK2H (DF / BK / 2)  // 32 (split-K half)
#define PBLK 768            // persistent blocks: 3 per CU

typedef __attribute__((ext_vector_type(4))) float f32x4;
typedef __attribute__((ext_vector_type(2))) float f32x2;
typedef __attribute__((ext_vector_type(8))) short s16x8;

// exact RNE fp32 -> bf16 (finite inputs)
static __device__ __forceinline__ unsigned short f2bf(float f) {
    unsigned int u = __float_as_uint(f);
    unsigned int r = u + 0x7fffu + ((u >> 16) & 1u);
    return (unsigned short)(r >> 16);
}

// packed RNE fp32x2 -> bf16x2 (single VALU op; layout verified R15/R16/R18)
static __device__ __forceinline__ unsigned int cvtpk(float lo, float hi) {
    unsigned int r;
    asm("v_cvt_pk_bf16_f32 %0, %1, %2" : "=v"(r) : "v"(lo), "v"(hi));
    return r;
}

// async global->LDS, 16B per lane; lds dest is wave-uniform base + lane*16
#define GLL(gsrc, ldst)                                                          \
    __builtin_amdgcn_global_load_lds(                                            \
        (const __attribute__((address_space(1))) void*)(gsrc),                   \
        (__attribute__((address_space(3))) void*)(ldst), 16, 0, 0)

// ---------------- gating ----------------

__global__ void k_transpose_gw(const float* __restrict__ gw, float* __restrict__ gwT) {
    int e = blockIdx.x;
    for (int d = threadIdx.x; d < DM; d += blockDim.x)
        gwT[e * DM + d] = gw[d * NE + e];
}

__global__ void k_gate(const float* __restrict__ x, const float* __restrict__ gwT,
                       const float* __restrict__ gb,
                       int* __restrict__ idx, float* __restrict__ prob) {
    int wave = threadIdx.x >> 6;
    int lane = threadIdx.x & 63;
    int t = blockIdx.x * 4 + wave;
    if (t >= T_TOK) return;
    const float* xr = x + (size_t)t * DM;
    float acc[NE];
#pragma unroll
    for (int e = 0; e < NE; e++) acc[e] = 0.f;
    for (int i = 0; i < DM / 64; i++) {
        int d = lane + i * 64;
        float xv = xr[d];
#pragma unroll
        for (int e = 0; e < NE; e++) acc[e] = fmaf(xv, gwT[e * DM + d], acc[e]);
    }
#pragma unroll
    for (int e = 0; e < NE; e++) {
        float v = acc[e];
        for (int off = 32; off >= 1; off >>= 1) v += __shfl_xor(v, off);
        acc[e] = v;
    }
    if (lane == 0) {
        float v1 = -1e30f, v2 = -1e30f;
        int i1 = -1, i2 = -1;
        for (int e = 0; e < NE; e++) {
            float s = acc[e] + gb[e];
            if (s > v1) { v2 = v1; i2 = i1; v1 = s; i1 = e; }
            else if (s > v2) { v2 = s; i2 = e; }
        }
        float e2 = expf(v2 - v1);
        float inv = 1.f / (1.f + e2);
        idx[t * 2] = i1; idx[t * 2 + 1] = i2;
        prob[t * 2] = inv; prob[t * 2 + 1] = e2 * inv;
    }
}

// ---------------- routing: count + scan + scatter + dense tile map --------------

__global__ __launch_bounds__(1024)
void k_route(const int* __restrict__ idx, int* __restrict__ counts,
             int* __restrict__ offsets, int* __restrict__ slot_tok,
             int* __restrict__ pair_slot, int* __restrict__ tmap,
             int* __restrict__ ntiles) {
    __shared__ int cnt[NE], offs[NE], cur[NE];
    const int tid = threadIdx.x;
    if (tid < NE) cnt[tid] = 0;
    __syncthreads();
    for (int i = tid; i < T2; i += 1024) atomicAdd(&cnt[idx[i]], 1);
    __syncthreads();
    if (tid == 0) {
        int s = 0, nt = 0;
        for (int e = 0; e < NE; e++) {
            offs[e] = s; offsets[e] = s; counts[e] = cnt[e]; s += cnt[e];
            for (int mt = 0; mt * BM < cnt[e]; mt++) tmap[nt++] = (e << 8) | mt;
        }
        ntiles[0] = nt;   // <= 24 + T2/BM = 88
    }
    if (tid < NE) cur[tid] = 0;
    __syncthreads();
    for (int i = tid; i < T2; i += 1024) {
        int e = idx[i];
        int pos = offs[e] + atomicAdd(&cur[e], 1);
        slot_tok[pos] = i >> 1;
        pair_slot[i] = pos;
    }
}

// gather routed token rows into dense bf16 slot-major matrix Xg[slot][DM]
__global__ void k_gather(const float* __restrict__ x, const int* __restrict__ slot_tok,
                         unsigned short* __restrict__ Xg) {
    int s = blockIdx.x;
    int tok = slot_tok[s];
    const float4* src = (const float4*)(x + (size_t)tok * DM);
    ushort4* dst = (ushort4*)(Xg + (size_t)s * DM);
    for (int i = threadIdx.x; i < DM / 4; i += blockDim.x) {
        float4 v = src[i];
        ushort4 o;
        o.x = f2bf(v.x); o.y = f2bf(v.y); o.z = f2bf(v.z); o.w = f2bf(v.w);
        dst[i] = o;
    }
}

// out[t] = p1*(Y1[s1]+Y2[s1]+b2[e1]) + p2*(Y1[s2]+Y2[s2]+b2[e2])
__global__ void k_combine(const float* __restrict__ Y1, const float* __restrict__ Y2,
                          const int* __restrict__ pair_slot,
                          const float* __restrict__ prob, const int* __restrict__ idx,
                          const float* __restrict__ b2, float* __restrict__ out) {
    int t = blockIdx.x;
    int s1 = pair_slot[t * 2], s2 = pair_slot[t * 2 + 1];
    int e1 = idx[t * 2], e2 = idx[t * 2 + 1];
    float p1 = prob[t * 2], p2 = prob[t * 2 + 1];
    const float4* y1a = (const float4*)(Y1 + (size_t)s1 * DM);
    const float4* y1b = (const float4*)(Y2 + (size_t)s1 * DM);
    const float4* y2a = (const float4*)(Y1 + (size_t)s2 * DM);
    const float4* y2b = (const float4*)(Y2 + (size_t)s2 * DM);
    const float4* ba = (const float4*)(b2 + (size_t)e1 * DM);
    const float4* bb = (const float4*)(b2 + (size_t)e2 * DM);
    float4* o = (float4*)(out + (size_t)t * DM);
    int i = threadIdx.x;
    float4 a0 = y1a[i], a1 = y1b[i], b0 = y2a[i], b1 = y2b[i];
    float4 c = ba[i], d = bb[i];
    float4 r;
    r.x = p1 * (a0.x + a1.x + c.x) + p2 * (b0.x + b1.x + d.x);
    r.y = p1 * (a0.y + a1.y + c.y) + p2 * (b0.y + b1.y + d.y);
    r.z = p1 * (a0.z + a1.z + c.z) + p2 * (b0.z + b1.z + d.z);
    r.w = p1 * (a0.w + a1.w + c.w) + p2 * (b0.w + b1.w + d.w);
    o[i] = r;
}

// ---------------- MM kernels: persistent blocks over dense tile map -------------
// 768 blocks (3/CU pinned by 48 KB LDS), 512 thr, R20 inner loop unchanged.
// Item space mm1: ntiles*32 (ti fastest -> block's items share W-panel n0);
// mm2: ntiles*16 (ti fastest; r = item/NT -> ksl = r&1, n0i = r>>1).
// Per-item prologue writes only As[0] (its last reads drained >=2 barriers ago);
// first in-loop __syncthreads (implicit vmcnt0/lgkm0) fences the rest.

__global__ __launch_bounds__(512)
void k_mm1(const unsigned short* __restrict__ Xg, const float* __restrict__ w1,
           const float* __restrict__ b1, const int* __restrict__ counts,
           const int* __restrict__ offsets, const int* __restrict__ tmap,
           const int* __restrict__ ntiles, unsigned short* __restrict__ H) {
    __shared__ unsigned short As[2][BM * BK];  // 2 x 16 KB bf16 [m][k] swizzled
    __shared__ unsigned short Bs[BN * BK];     // 16 KB bf16 [n][k] swizzled

    const int tid  = threadIdx.x;
    const int lane = tid & 63;
    const int w    = tid >> 6;               // 0..7
    const int wm   = w >> 1, wn = w & 1;

    const int arow = lane >> 3;
    const int gchunk = ((lane & 7) ^ arow) * 8;
    const int swz0 = ((lane >> 4) ^ (lane & 7)) << 4;
    const int swz1 = ((4 | (lane >> 4)) ^ (lane & 7)) << 4;
    const char* Arow0 = (const char*)As[0] + (wm * 32 + (lane & 15)) * 128;
    const char* Arow1 = (const char*)As[1] + (wm * 32 + (lane & 15)) * 128;
    const char* Brow  = (const char*)Bs + (wn * 64 + (lane & 15)) * 128;

    const int np = (tid & 63) * 2;
    const int ckw = w;
    char* BsW0 = (char*)Bs + (np + 0) * 128 + ((ckw ^ ((np + 0) & 7)) << 4);
    char* BsW1 = (char*)Bs + (np + 1) * 128 + ((ckw ^ ((np + 1) & 7)) << 4);

    const int NT = ntiles[0];
    const int TOTW = NT * 32;
    const int CS = (TOTW + PBLK - 1) / PBLK;
    const int i0 = blockIdx.x * CS;
    const int i1 = min(i0 + CS, TOTW);

#pragma unroll 1
    for (int item = i0; item < i1; ++item) {
        const int ti = item % NT;
        const int n0 = (item / NT) * BN;
        const int tm = tmap[ti];
        const int e = tm >> 8, mt = tm & 255;
        const int ne = counts[e];
        const int m0 = mt * BM;
        const int rows = min(BM, ne - m0);
        const int slotbase = offsets[e] + m0;
        const float* w1e = w1 + (size_t)e * DM * DF;

        f32x4 acc[2][4];
#pragma unroll
        for (int a = 0; a < 2; a++)
#pragma unroll
            for (int b = 0; b < 4; b++) acc[a][b] = (f32x4)0.f;

        f32x2 L[8];
        auto loadB = [&](int k0) {
#pragma unroll
            for (int j = 0; j < 8; j++)
                L[j] = *(const f32x2*)(w1e + (size_t)(k0 + w * 8 + j) * DF + n0 + np);
        };
        auto stageA = [&](int buf, int k0) {
#pragma unroll
            for (int q = 0; q < 2; q++) {
                int row = (w * 2 + q) * 8 + arow;
                GLL(Xg + (size_t)(slotbase + row) * DM + k0 + gchunk,
                    &As[buf][(w * 2 + q) * 512]);
            }
        };

        stageA(0, 0);
        loadB(0);
#pragma unroll 1
        for (int kt = 0; kt < NK1; ++kt) {
            const int cur = kt & 1;
            __syncthreads();                           // kt loads landed
            if (kt + 1 < NK1) stageA(cur ^ 1, (kt + 1) * BK);
            {
                uint4 v0, v1;
                v0.x = cvtpk(L[0][0], L[1][0]);
                v0.y = cvtpk(L[2][0], L[3][0]);
                v0.z = cvtpk(L[4][0], L[5][0]);
                v0.w = cvtpk(L[6][0], L[7][0]);
                v1.x = cvtpk(L[0][1], L[1][1]);
                v1.y = cvtpk(L[2][1], L[3][1]);
                v1.z = cvtpk(L[4][1], L[5][1]);
                v1.w = cvtpk(L[6][1], L[7][1]);
                *(uint4*)BsW0 = v0;
                *(uint4*)BsW1 = v1;
            }
            if (kt + 1 < NK1) loadB((kt + 1) * BK);    // in flight across raw barrier
            const char* Arow = cur ? Arow1 : Arow0;
            s16x8 af[2][2];
#pragma unroll
            for (int f = 0; f < 2; f++) {
                af[0][f] = *(const s16x8*)(Arow + f * 2048 + swz0);
                af[1][f] = *(const s16x8*)(Arow + f * 2048 + swz1);
            }
            asm volatile("s_waitcnt lgkmcnt(0)" ::: "memory");
            __builtin_amdgcn_s_barrier();
            __builtin_amdgcn_sched_barrier(0);
            s16x8 bfr[2][4];
#pragma unroll
            for (int f = 0; f < 4; f++) {
                bfr[0][f] = *(const s16x8*)(Brow + f * 2048 + swz0);
                bfr[1][f] = *(const s16x8*)(Brow + f * 2048 + swz1);
            }
#pragma unroll
            for (int ks = 0; ks < 2; ks++)
#pragma unroll
                for (int fm = 0; fm < 2; fm++)
#pragma unroll
                    for (int fn = 0; fn < 4; fn++)
                        acc[fm][fn] = __builtin_amdgcn_mfma_f32_16x16x32_bf16(
                            af[ks][fm], bfr[ks][fn], acc[fm][fn], 0, 0, 0);
        }

        const float* b1e = b1 + (size_t)e * DF;
#pragma unroll
        for (int fm = 0; fm < 2; fm++) {
            const int mrow = wm * 32 + fm * 16 + ((lane >> 4) << 2);
#pragma unroll
            for (int fn = 0; fn < 4; fn++) {
                const int ncol = n0 + wn * 64 + fn * 16 + (lane & 15);
                const float bb = b1e[ncol];
#pragma unroll
                for (int r = 0; r < 4; r++) {
                    const int m = mrow + r;
                    if (m < rows) {
                        float h = acc[fm][fn][r] + bb;
                        h = 0.5f * h * (1.f + erff(h * 0.70710678118654752f));
                        H[(size_t)(slotbase + m) * DF + ncol] = f2bf(h);
                    }
                }
            }
        }
    }
}

__global__ __launch_bounds__(512)
void k_mm2(const unsigned short* __restrict__ Hb, const float* __restrict__ w2,
           const int* __restrict__ counts, const int* __restrict__ offsets,
           const int* __restrict__ tmap, const int* __restrict__ ntiles,
           float* __restrict__ Y1, float* __restrict__ Y2) {
    __shared__ unsigned short As[2][BM * BK];
    __shared__ unsigned short Bs[BN * BK];

    const int tid  = threadIdx.x;
    const int lane = tid & 63;
    const int w    = tid >> 6;
    const int wm   = w >> 1, wn = w & 1;

    const int arow = lane >> 3;
    const int gchunk = ((lane & 7) ^ arow) * 8;
    const int swz0 = ((lane >> 4) ^ (lane & 7)) << 4;
    const int swz1 = ((4 | (lane >> 4)) ^ (lane & 7)) << 4;
    const char* Arow0 = (const char*)As[0] + (wm * 32 + (lane & 15)) * 128;
    const char* Arow1 = (const char*)As[1] + (wm * 32 + (lane & 15)) * 128;
    const char* Brow  = (const char*)Bs + (wn * 64 + (lane & 15)) * 128;

    const int np = (tid & 63) * 2;
    const int ckw = w;
    char* BsW0 = (char*)Bs + (np + 0) * 128 + ((ckw ^ ((np + 0) & 7)) << 4);
    char* BsW1 = (char*)Bs + (np + 1) * 128 + ((ckw ^ ((np + 1) & 7)) << 4);

    const int NT = ntiles[0];
    const int TOTW = NT * 16;                 // 8 n-chunks x 2 ksl
    const int CS = (TOTW + PBLK - 1) / PBLK;
    const int i0 = blockIdx.x * CS;
    const int i1 = min(i0 + CS, TOTW);

#pragma unroll 1
    for (int item = i0; item < i1; ++item) {
        const int ti = item % NT;
        const int r2 = item / NT;
        const int ksl = r2 & 1;
        const int n0 = (r2 >> 1) * BN;
        const int tm = tmap[ti];
        const int e = tm >> 8, mt = tm & 255;
        const int ne = counts[e];
        const int m0 = mt * BM;
        const int rows = min(BM, ne - m0);
        const int slotbase = offsets[e] + m0;
        const int kbeg = ksl * (DF / 2);
        float* Y = ksl ? Y2 : Y1;
        const float* w2e = w2 + (size_t)e * DF * DM;

        f32x4 acc[2][4];
#pragma unroll
        for (int a = 0; a < 2; a++)
#pragma unroll
            for (int b = 0; b < 4; b++) acc[a][b] = (f32x4)0.f;

        f32x2 L[8];
        auto loadB = [&](int k0) {
#pragma unroll
            for (int j = 0; j < 8; j++)
                L[j] = *(const f32x2*)(w2e + (size_t)(k0 + w * 8 + j) * DM + n0 + np);
        };
        auto stageA = [&](int buf, int k0) {
#pragma unroll
            for (int q = 0; q < 2; q++) {
                int row = (w * 2 + q) * 8 + arow;
                GLL(Hb + (size_t)(slotbase + row) * DF + k0 + gchunk,
                    &As[buf][(w * 2 + q) * 512]);
            }
        };

        stageA(0, kbeg);
        loadB(kbeg);
#pragma unroll 1
        for (int kt = 0; kt < NK2H; ++kt) {
            const int cur = kt & 1;
            __syncthreads();
            if (kt + 1 < NK2H) stageA(cur ^ 1, kbeg + (kt + 1) * BK);
            {
                uint4 v0, v1;
                v0.x = cvtpk(L[0][0], L[1][0]);
                v0.y = cvtpk(L[2][0], L[3][0]);
                v0.z = cvtpk(L[4][0], L[5][0]);
                v0.w = cvtpk(L[6][0], L[7][0]);
                v1.x = cvtpk(L[0][1], L[1][1]);
                v1.y = cvtpk(L[2][1], L[3][1]);
                v1.z = cvtpk(L[4][1], L[5][1]);
                v1.w = cvtpk(L[6][1], L[7][1]);
                *(uint4*)BsW0 = v0;
                *(uint4*)BsW1 = v1;
            }
            if (kt + 1 < NK2H) loadB(kbeg + (kt + 1) * BK);
            const char* Arow = cur ? Arow1 : Arow0;
            s16x8 af[2][2];
#pragma unroll
            for (int f = 0; f < 2; f++) {
                af[0][f] = *(const s16x8*)(Arow + f * 2048 + swz0);
                af[1][f] = *(const s16x8*)(Arow + f * 2048 + swz1);
            }
            asm volatile("s_waitcnt lgkmcnt(0)" ::: "memory");
            __builtin_amdgcn_s_barrier();
            __builtin_amdgcn_sched_barrier(0);
            s16x8 bfr[2][4];
#pragma unroll
            for (int f = 0; f < 4; f++) {
                bfr[0][f] = *(const s16x8*)(Brow + f * 2048 + swz0);
                bfr[1][f] = *(const s16x8*)(Brow + f * 2048 + swz1);
            }
#pragma unroll
            for (int ks = 0; ks < 2; ks++)
#pragma unroll
                for (int fm = 0; fm < 2; fm++)
#pragma unroll
                    for (int fn = 0; fn < 4; fn++)
                        acc[fm][fn] = __builtin_amdgcn_mfma_f32_16x16x32_bf16(
                            af[ks][fm], bfr[ks][fn], acc[fm][fn], 0, 0, 0);
        }

#pragma unroll
        for (int fm = 0; fm < 2; fm++) {
            const int mrow = wm * 32 + fm * 16 + ((lane >> 4) << 2);
#pragma unroll
            for (int fn = 0; fn < 4; fn++) {
                const int ncol = n0 + wn * 64 + fn * 16 + (lane & 15);
#pragma unroll
                for (int r = 0; r < 4; r++) {
                    const int m = mrow + r;
                    if (m < rows)
                        Y[(size_t)(slotbase + m) * DM + ncol] = acc[fm][fn][r];
                }
            }
        }
    }
}

// ---------------- launch ----------------

extern "C" void kernel_launch(void* const* d_in, const int* in_sizes, int n_in,
                              void* d_out, int out_size, void* d_ws, size_t ws_size,
                              hipStream_t stream) {
    const float* x   = (const float*)d_in[0];
    const float* gw  = (const float*)d_in[1];
    const float* gb  = (const float*)d_in[2];
    const float* w1  = (const float*)d_in[3];
    const float* b1  = (const float*)d_in[4];
    const float* w2  = (const float*)d_in[5];
    const float* b2  = (const float*)d_in[6];
    float* out = (float*)d_out;

    size_t off = 0;
    auto alloc = [&](size_t bytes) {
        void* p = (char*)d_ws + off;
        off += (bytes + 255) & ~(size_t)255;
        return p;
    };
    float* gwT       = (float*)alloc(NE * DM * sizeof(float));
    int*   idx       = (int*)alloc(T2 * sizeof(int));
    float* prob      = (float*)alloc(T2 * sizeof(float));
    int*   counts    = (int*)alloc(32 * sizeof(int));
    int*   offsets   = (int*)alloc(32 * sizeof(int));
    int*   slot_tok  = (int*)alloc(T2 * sizeof(int));
    int*   pair_slot = (int*)alloc(T2 * sizeof(int));
    int*   tmap      = (int*)alloc(128 * sizeof(int));
    int*   ntiles    = (int*)alloc(32 * sizeof(int));
    unsigned short* Xg = (unsigned short*)alloc((size_t)(T2 + BM) * DM * sizeof(unsigned short));
    unsigned short* Hb = (unsigned short*)alloc((size_t)(T2 + BM) * DF * sizeof(unsigned short));
    float* Yb        = (float*)alloc((size_t)(T2 + BM) * DM * sizeof(float));
    float* Yb2       = (float*)alloc((size_t)(T2 + BM) * DM * sizeof(float));

    k_transpose_gw<<<NE, 256, 0, stream>>>(gw, gwT);
    k_gate<<<T_TOK / 4, 256, 0, stream>>>(x, gwT, gb, idx, prob);
    k_route<<<1, 1024, 0, stream>>>(idx, counts, offsets, slot_tok, pair_slot, tmap, ntiles);
    k_gather<<<T2, 256, 0, stream>>>(x, slot_tok, Xg);

    k_mm1<<<PBLK, 512, 0, stream>>>(Xg, w1, b1, counts, offsets, tmap, ntiles, Hb);
    k_mm2<<<PBLK, 512, 0, stream>>>(Hb, w2, counts, offsets, tmap, ntiles, Yb, Yb2);
    k_combine<<<T_TOK, 256, 0, stream>>>(Yb, Yb2, pair_slot, prob, idx, b2, out);
}

// Round 22
// 465.278 us; speedup vs baseline: 1.3230x; 1.3230x over previous
//
#include <hip/hip_runtime.h>
#include <math.h>

#define DM 1024
#define DF 4096
#define NE 24
#define T_TOK 4096
#define T2 (T_TOK*2)

#define BM 128
#define BN 128
#define BK 64
#define NK1 (DM / BK)       // 16
#define NK2H (DF / BK / 2)  // 32 (split-K half)
#define NTMAX 88            // max tiles: 24 + 8192/128

typedef __attribute__((ext_vector_type(4))) float f32x4;
typedef __attribute__((ext_vector_type(2))) float f32x2;
typedef __attribute__((ext_vector_type(8))) short s16x8;

// exact RNE fp32 -> bf16 (finite inputs)
static __device__ __forceinline__ unsigned short f2bf(float f) {
    unsigned int u = __float_as_uint(f);
    unsigned int r = u + 0x7fffu + ((u >> 16) & 1u);
    return (unsigned short)(r >> 16);
}

// packed RNE fp32x2 -> bf16x2 (single VALU op; layout verified R15/R16/R18)
static __device__ __forceinline__ unsigned int cvtpk(float lo, float hi) {
    unsigned int r;
    asm("v_cvt_pk_bf16_f32 %0, %1, %2" : "=v"(r) : "v"(lo), "v"(hi));
    return r;
}

// async global->LDS, 16B per lane; lds dest is wave-uniform base + lane*16
#define GLL(gsrc, ldst)                                                          \
    __builtin_amdgcn_global_load_lds(                                            \
        (const __attribute__((address_space(1))) void*)(gsrc),                   \
        (__attribute__((address_space(3))) void*)(ldst), 16, 0, 0)

// ---------------- gating ----------------

__global__ void k_transpose_gw(const float* __restrict__ gw, float* __restrict__ gwT) {
    int e = blockIdx.x;
    for (int d = threadIdx.x; d < DM; d += blockDim.x)
        gwT[e * DM + d] = gw[d * NE + e];
}

__global__ void k_gate(const float* __restrict__ x, const float* __restrict__ gwT,
                       const float* __restrict__ gb,
                       int* __restrict__ idx, float* __restrict__ prob) {
    int wave = threadIdx.x >> 6;
    int lane = threadIdx.x & 63;
    int t = blockIdx.x * 4 + wave;
    if (t >= T_TOK) return;
    const float* xr = x + (size_t)t * DM;
    float acc[NE];
#pragma unroll
    for (int e = 0; e < NE; e++) acc[e] = 0.f;
    for (int i = 0; i < DM / 64; i++) {
        int d = lane + i * 64;
        float xv = xr[d];
#pragma unroll
        for (int e = 0; e < NE; e++) acc[e] = fmaf(xv, gwT[e * DM + d], acc[e]);
    }
#pragma unroll
    for (int e = 0; e < NE; e++) {
        float v = acc[e];
        for (int off = 32; off >= 1; off >>= 1) v += __shfl_xor(v, off);
        acc[e] = v;
    }
    if (lane == 0) {
        float v1 = -1e30f, v2 = -1e30f;
        int i1 = -1, i2 = -1;
        for (int e = 0; e < NE; e++) {
            float s = acc[e] + gb[e];
            if (s > v1) { v2 = v1; i2 = i1; v1 = s; i1 = e; }
            else if (s > v2) { v2 = s; i2 = e; }
        }
        float e2 = expf(v2 - v1);
        float inv = 1.f / (1.f + e2);
        idx[t * 2] = i1; idx[t * 2 + 1] = i2;
        prob[t * 2] = inv; prob[t * 2 + 1] = e2 * inv;
    }
}

// ---------------- routing: count + scan + scatter + dense tile map --------------

__global__ __launch_bounds__(1024)
void k_route(const int* __restrict__ idx, int* __restrict__ counts,
             int* __restrict__ offsets, int* __restrict__ slot_tok,
             int* __restrict__ pair_slot, int* __restrict__ tmap,
             int* __restrict__ ntiles) {
    __shared__ int cnt[NE], offs[NE], cur[NE];
    const int tid = threadIdx.x;
    if (tid < NE) cnt[tid] = 0;
    __syncthreads();
    for (int i = tid; i < T2; i += 1024) atomicAdd(&cnt[idx[i]], 1);
    __syncthreads();
    if (tid == 0) {
        int s = 0, nt = 0;
        for (int e = 0; e < NE; e++) {
            offs[e] = s; offsets[e] = s; counts[e] = cnt[e]; s += cnt[e];
            for (int mt = 0; mt * BM < cnt[e]; mt++) tmap[nt++] = (e << 8) | mt;
        }
        ntiles[0] = nt;   // <= NTMAX
    }
    if (tid < NE) cur[tid] = 0;
    __syncthreads();
    for (int i = tid; i < T2; i += 1024) {
        int e = idx[i];
        int pos = offs[e] + atomicAdd(&cur[e], 1);
        slot_tok[pos] = i >> 1;
        pair_slot[i] = pos;
    }
}

// gather routed token rows into dense bf16 slot-major matrix Xg[slot][DM]
__global__ void k_gather(const float* __restrict__ x, const int* __restrict__ slot_tok,
                         unsigned short* __restrict__ Xg) {
    int s = blockIdx.x;
    int tok = slot_tok[s];
    const float4* src = (const float4*)(x + (size_t)tok * DM);
    ushort4* dst = (ushort4*)(Xg + (size_t)s * DM);
    for (int i = threadIdx.x; i < DM / 4; i += blockDim.x) {
        float4 v = src[i];
        ushort4 o;
        o.x = f2bf(v.x); o.y = f2bf(v.y); o.z = f2bf(v.z); o.w = f2bf(v.w);
        dst[i] = o;
    }
}

// out[t] = p1*(Y1[s1]+Y2[s1]+b2[e1]) + p2*(Y1[s2]+Y2[s2]+b2[e2])
__global__ void k_combine(const float* __restrict__ Y1, const float* __restrict__ Y2,
                          const int* __restrict__ pair_slot,
                          const float* __restrict__ prob, const int* __restrict__ idx,
                          const float* __restrict__ b2, float* __restrict__ out) {
    int t = blockIdx.x;
    int s1 = pair_slot[t * 2], s2 = pair_slot[t * 2 + 1];
    int e1 = idx[t * 2], e2 = idx[t * 2 + 1];
    float p1 = prob[t * 2], p2 = prob[t * 2 + 1];
    const float4* y1a = (const float4*)(Y1 + (size_t)s1 * DM);
    const float4* y1b = (const float4*)(Y2 + (size_t)s1 * DM);
    const float4* y2a = (const float4*)(Y1 + (size_t)s2 * DM);
    const float4* y2b = (const float4*)(Y2 + (size_t)s2 * DM);
    const float4* ba = (const float4*)(b2 + (size_t)e1 * DM);
    const float4* bb = (const float4*)(b2 + (size_t)e2 * DM);
    float4* o = (float4*)(out + (size_t)t * DM);
    int i = threadIdx.x;
    float4 a0 = y1a[i], a1 = y1b[i], b0 = y2a[i], b1 = y2b[i];
    float4 c = ba[i], d = bb[i];
    float4 r;
    r.x = p1 * (a0.x + a1.x + c.x) + p2 * (b0.x + b1.x + d.x);
    r.y = p1 * (a0.y + a1.y + c.y) + p2 * (b0.y + b1.y + d.y);
    r.z = p1 * (a0.z + a1.z + c.z) + p2 * (b0.z + b1.z + d.z);
    r.w = p1 * (a0.w + a1.w + c.w) + p2 * (b0.w + b1.w + d.w);
    o[i] = r;
}

// ---------------- MM kernels: dense compacted grid, one item per block ----------
// R20 inner loop byte-identical; decode via tmap. Grid mm1 = NTMAX*32 (18% empty
// vs R20's 62%), mm2 = NTMAX*16. XCD swizzle with ti FASTEST: blocks sharing the
// same (e,n0) W-panel are adjacent -> same XCD -> CONCURRENT L2 sharing (R21's
// serial per-block chaining tripled FETCH; this restores R20's traffic shape).

__global__ __launch_bounds__(512)
void k_mm1(const unsigned short* __restrict__ Xg, const float* __restrict__ w1,
           const float* __restrict__ b1, const int* __restrict__ counts,
           const int* __restrict__ offsets, const int* __restrict__ tmap,
           const int* __restrict__ ntiles, unsigned short* __restrict__ H) {
    const int TOT = NTMAX * 32;                              // 2816
    int work = (blockIdx.x & 7) * (TOT >> 3) + (blockIdx.x >> 3);
    const int ti = work % NTMAX;
    if (ti >= ntiles[0]) return;
    const int n0 = (work / NTMAX) * BN;
    const int tm = tmap[ti];
    const int e = tm >> 8, mt = tm & 255;
    const int ne = counts[e];
    const int m0 = mt * BM;
    const int rows = min(BM, ne - m0);
    const int slotbase = offsets[e] + m0;

    __shared__ unsigned short As[2][BM * BK];  // 2 x 16 KB bf16 [m][k] swizzled
    __shared__ unsigned short Bs[BN * BK];     // 16 KB bf16 [n][k] swizzled

    const int tid  = threadIdx.x;
    const int lane = tid & 63;
    const int w    = tid >> 6;               // 0..7
    const int wm   = w >> 1, wn = w & 1;

    const float* w1e = w1 + (size_t)e * DM * DF;
    const int arow = lane >> 3;
    const int gchunk = ((lane & 7) ^ arow) * 8;

    const int swz0 = ((lane >> 4) ^ (lane & 7)) << 4;
    const int swz1 = ((4 | (lane >> 4)) ^ (lane & 7)) << 4;
    const char* Arow0 = (const char*)As[0] + (wm * 32 + (lane & 15)) * 128;
    const char* Arow1 = (const char*)As[1] + (wm * 32 + (lane & 15)) * 128;
    const char* Brow  = (const char*)Bs + (wn * 64 + (lane & 15)) * 128;

    const int np = (tid & 63) * 2;
    const int ckw = w;
    char* BsW0 = (char*)Bs + (np + 0) * 128 + ((ckw ^ ((np + 0) & 7)) << 4);
    char* BsW1 = (char*)Bs + (np + 1) * 128 + ((ckw ^ ((np + 1) & 7)) << 4);

    f32x4 acc[2][4];
#pragma unroll
    for (int a = 0; a < 2; a++)
#pragma unroll
        for (int b = 0; b < 4; b++) acc[a][b] = (f32x4)0.f;

    f32x2 L[8];
    auto loadB = [&](int k0) {
#pragma unroll
        for (int j = 0; j < 8; j++)
            L[j] = *(const f32x2*)(w1e + (size_t)(k0 + w * 8 + j) * DF + n0 + np);
    };
    auto stageA = [&](int buf, int k0) {
#pragma unroll
        for (int q = 0; q < 2; q++) {
            int row = (w * 2 + q) * 8 + arow;
            GLL(Xg + (size_t)(slotbase + row) * DM + k0 + gchunk,
                &As[buf][(w * 2 + q) * 512]);
        }
    };

    stageA(0, 0);
    loadB(0);
#pragma unroll 1
    for (int kt = 0; kt < NK1; ++kt) {
        const int cur = kt & 1;
        __syncthreads();                               // kt loads landed
        if (kt + 1 < NK1) stageA(cur ^ 1, (kt + 1) * BK);
        {
            uint4 v0, v1;
            v0.x = cvtpk(L[0][0], L[1][0]);
            v0.y = cvtpk(L[2][0], L[3][0]);
            v0.z = cvtpk(L[4][0], L[5][0]);
            v0.w = cvtpk(L[6][0], L[7][0]);
            v1.x = cvtpk(L[0][1], L[1][1]);
            v1.y = cvtpk(L[2][1], L[3][1]);
            v1.z = cvtpk(L[4][1], L[5][1]);
            v1.w = cvtpk(L[6][1], L[7][1]);
            *(uint4*)BsW0 = v0;
            *(uint4*)BsW1 = v1;
        }
        if (kt + 1 < NK1) loadB((kt + 1) * BK);        // in flight across raw barrier
        const char* Arow = cur ? Arow1 : Arow0;
        s16x8 af[2][2];
#pragma unroll
        for (int f = 0; f < 2; f++) {
            af[0][f] = *(const s16x8*)(Arow + f * 2048 + swz0);
            af[1][f] = *(const s16x8*)(Arow + f * 2048 + swz1);
        }
        asm volatile("s_waitcnt lgkmcnt(0)" ::: "memory");
        __builtin_amdgcn_s_barrier();
        __builtin_amdgcn_sched_barrier(0);
        s16x8 bfr[2][4];
#pragma unroll
        for (int f = 0; f < 4; f++) {
            bfr[0][f] = *(const s16x8*)(Brow + f * 2048 + swz0);
            bfr[1][f] = *(const s16x8*)(Brow + f * 2048 + swz1);
        }
#pragma unroll
        for (int ks = 0; ks < 2; ks++)
#pragma unroll
            for (int fm = 0; fm < 2; fm++)
#pragma unroll
                for (int fn = 0; fn < 4; fn++)
                    acc[fm][fn] = __builtin_amdgcn_mfma_f32_16x16x32_bf16(
                        af[ks][fm], bfr[ks][fn], acc[fm][fn], 0, 0, 0);
    }

    const float* b1e = b1 + (size_t)e * DF;
#pragma unroll
    for (int fm = 0; fm < 2; fm++) {
        const int mrow = wm * 32 + fm * 16 + ((lane >> 4) << 2);
#pragma unroll
        for (int fn = 0; fn < 4; fn++) {
            const int ncol = n0 + wn * 64 + fn * 16 + (lane & 15);
            const float bb = b1e[ncol];
#pragma unroll
            for (int r = 0; r < 4; r++) {
                const int m = mrow + r;
                if (m < rows) {
                    float h = acc[fm][fn][r] + bb;
                    h = 0.5f * h * (1.f + erff(h * 0.70710678118654752f));
                    H[(size_t)(slotbase + m) * DF + ncol] = f2bf(h);
                }
            }
        }
    }
}

__global__ __launch_bounds__(512)
void k_mm2(const unsigned short* __restrict__ Hb, const float* __restrict__ w2,
           const int* __restrict__ counts, const int* __restrict__ offsets,
           const int* __restrict__ tmap, const int* __restrict__ ntiles,
           float* __restrict__ Y1, float* __restrict__ Y2) {
    const int TOT = NTMAX * 16;                              // 1408
    int work = (blockIdx.x & 7) * (TOT >> 3) + (blockIdx.x >> 3);
    const int ti = work % NTMAX;
    if (ti >= ntiles[0]) return;
    const int r2 = work / NTMAX;
    const int ksl = r2 & 1;
    const int n0 = (r2 >> 1) * BN;
    const int tm = tmap[ti];
    const int e = tm >> 8, mt = tm & 255;
    const int ne = counts[e];
    const int m0 = mt * BM;
    const int rows = min(BM, ne - m0);
    const int slotbase = offsets[e] + m0;
    const int kbeg = ksl * (DF / 2);
    float* Y = ksl ? Y2 : Y1;

    __shared__ unsigned short As[2][BM * BK];
    __shared__ unsigned short Bs[BN * BK];

    const int tid  = threadIdx.x;
    const int lane = tid & 63;
    const int w    = tid >> 6;
    const int wm   = w >> 1, wn = w & 1;

    const float* w2e = w2 + (size_t)e * DF * DM;
    const int arow = lane >> 3;
    const int gchunk = ((lane & 7) ^ arow) * 8;

    const int swz0 = ((lane >> 4) ^ (lane & 7)) << 4;
    const int swz1 = ((4 | (lane >> 4)) ^ (lane & 7)) << 4;
    const char* Arow0 = (const char*)As[0] + (wm * 32 + (lane & 15)) * 128;
    const char* Arow1 = (const char*)As[1] + (wm * 32 + (lane & 15)) * 128;
    const char* Brow  = (const char*)Bs + (wn * 64 + (lane & 15)) * 128;

    const int np = (tid & 63) * 2;
    const int ckw = w;
    char* BsW0 = (char*)Bs + (np + 0) * 128 + ((ckw ^ ((np + 0) & 7)) << 4);
    char* BsW1 = (char*)Bs + (np + 1) * 128 + ((ckw ^ ((np + 1) & 7)) << 4);

    f32x4 acc[2][4];
#pragma unroll
    for (int a = 0; a < 2; a++)
#pragma unroll
        for (int b = 0; b < 4; b++) acc[a][b] = (f32x4)0.f;

    f32x2 L[8];
    auto loadB = [&](int k0) {
#pragma unroll
        for (int j = 0; j < 8; j++)
            L[j] = *(const f32x2*)(w2e + (size_t)(k0 + w * 8 + j) * DM + n0 + np);
    };
    auto stageA = [&](int buf, int k0) {
#pragma unroll
        for (int q = 0; q < 2; q++) {
            int row = (w * 2 + q) * 8 + arow;
            GLL(Hb + (size_t)(slotbase + row) * DF + k0 + gchunk,
                &As[buf][(w * 2 + q) * 512]);
        }
    };

    stageA(0, kbeg);
    loadB(kbeg);
#pragma unroll 1
    for (int kt = 0; kt < NK2H; ++kt) {
        const int cur = kt & 1;
        __syncthreads();
        if (kt + 1 < NK2H) stageA(cur ^ 1, kbeg + (kt + 1) * BK);
        {
            uint4 v0, v1;
            v0.x = cvtpk(L[0][0], L[1][0]);
            v0.y = cvtpk(L[2][0], L[3][0]);
            v0.z = cvtpk(L[4][0], L[5][0]);
            v0.w = cvtpk(L[6][0], L[7][0]);
            v1.x = cvtpk(L[0][1], L[1][1]);
            v1.y = cvtpk(L[2][1], L[3][1]);
            v1.z = cvtpk(L[4][1], L[5][1]);
            v1.w = cvtpk(L[6][1], L[7][1]);
            *(uint4*)BsW0 = v0;
            *(uint4*)BsW1 = v1;
        }
        if (kt + 1 < NK2H) loadB(kbeg + (kt + 1) * BK);
        const char* Arow = cur ? Arow1 : Arow0;
        s16x8 af[2][2];
#pragma unroll
        for (int f = 0; f < 2; f++) {
            af[0][f] = *(const s16x8*)(Arow + f * 2048 + swz0);
            af[1][f] = *(const s16x8*)(Arow + f * 2048 + swz1);
        }
        asm volatile("s_waitcnt lgkmcnt(0)" ::: "memory");
        __builtin_amdgcn_s_barrier();
        __builtin_amdgcn_sched_barrier(0);
        s16x8 bfr[2][4];
#pragma unroll
        for (int f = 0; f < 4; f++) {
            bfr[0][f] = *(const s16x8*)(Brow + f * 2048 + swz0);
            bfr[1][f] = *(const s16x8*)(Brow + f * 2048 + swz1);
        }
#pragma unroll
        for (int ks = 0; ks < 2; ks++)
#pragma unroll
            for (int fm = 0; fm < 2; fm++)
#pragma unroll
                for (int fn = 0; fn < 4; fn++)
                    acc[fm][fn] = __builtin_amdgcn_mfma_f32_16x16x32_bf16(
                        af[ks][fm], bfr[ks][fn], acc[fm][fn], 0, 0, 0);
    }

#pragma unroll
    for (int fm = 0; fm < 2; fm++) {
        const int mrow = wm * 32 + fm * 16 + ((lane >> 4) << 2);
#pragma unroll
        for (int fn = 0; fn < 4; fn++) {
            const int ncol = n0 + wn * 64 + fn * 16 + (lane & 15);
#pragma unroll
            for (int r = 0; r < 4; r++) {
                const int m = mrow + r;
                if (m < rows)
                    Y[(size_t)(slotbase + m) * DM + ncol] = acc[fm][fn][r];
            }
        }
    }
}

// ---------------- launch ----------------

extern "C" void kernel_launch(void* const* d_in, const int* in_sizes, int n_in,
                              void* d_out, int out_size, void* d_ws, size_t ws_size,
                              hipStream_t stream) {
    const float* x   = (const float*)d_in[0];
    const float* gw  = (const float*)d_in[1];
    const float* gb  = (const float*)d_in[2];
    const float* w1  = (const float*)d_in[3];
    const float* b1  = (const float*)d_in[4];
    const float* w2  = (const float*)d_in[5];
    const float* b2  = (const float*)d_in[6];
    float* out = (float*)d_out;

    size_t off = 0;
    auto alloc = [&](size_t bytes) {
        void* p = (char*)d_ws + off;
        off += (bytes + 255) & ~(size_t)255;
        return p;
    };
    float* gwT       = (float*)alloc(NE * DM * sizeof(float));
    int*   idx       = (int*)alloc(T2 * sizeof(int));
    float* prob      = (float*)alloc(T2 * sizeof(float));
    int*   counts    = (int*)alloc(32 * sizeof(int));
    int*   offsets   = (int*)alloc(32 * sizeof(int));
    int*   slot_tok  = (int*)alloc(T2 * sizeof(int));
    int*   pair_slot = (int*)alloc(T2 * sizeof(int));
    int*   tmap      = (int*)alloc(128 * sizeof(int));
    int*   ntiles    = (int*)alloc(32 * sizeof(int));
    unsigned short* Xg = (unsigned short*)alloc((size_t)(T2 + BM) * DM * sizeof(unsigned short));
    unsigned short* Hb = (unsigned short*)alloc((size_t)(T2 + BM) * DF * sizeof(unsigned short));
    float* Yb        = (float*)alloc((size_t)(T2 + BM) * DM * sizeof(float));
    float* Yb2       = (float*)alloc((size_t)(T2 + BM) * DM * sizeof(float));

    k_transpose_gw<<<NE, 256, 0, stream>>>(gw, gwT);
    k_gate<<<T_TOK / 4, 256, 0, stream>>>(x, gwT, gb, idx, prob);
    k_route<<<1, 1024, 0, stream>>>(idx, counts, offsets, slot_tok, pair_slot, tmap, ntiles);
    k_gather<<<T2, 256, 0, stream>>>(x, slot_tok, Xg);

    k_mm1<<<NTMAX * 32, 512, 0, stream>>>(Xg, w1, b1, counts, offsets, tmap, ntiles, Hb);
    k_mm2<<<NTMAX * 16, 512, 0, stream>>>(Hb, w2, counts, offsets, tmap, ntiles, Yb, Yb2);
    k_combine<<<T_TOK, 256, 0, stream>>>(Yb, Yb2, pair_slot, prob, idx, b2, out);
}